// Round 7
// baseline (471.910 us; speedup 1.0000x reference)
//
#include <hip/hip_runtime.h>

// LIF spike scan: x[N, T=32] fp32, scan over contiguous T axis.
//   u = 0.25*u*(1-o_prev) + x_t ;  o = (u > 0.5) ? 1 : 0
// 0.25*u exact (pow2), (1-o) in {0,1} exact -> bit-exact vs numpy fp32 ref.
//
// R7: DMA-pipelined persistent kernel.
//  R4/R6 post-mortem: VGPR=36/44 proves the register allocator never kept
//  register prefetches live across the scan -> no round ever pipelined ->
//  all plateau at ~2.4 TB/s (= ~40% memory duty x 6.3 TB/s achievable).
//  global_load_lds uses NO result VGPRs and is side-effecting: the compiler
//  cannot sink it and RA cannot kill it. Double-buffered LDS (static names
//  A/B so alias analysis can't inject vmcnt(0) drains), raw s_barrier +
//  fine-grained s_waitcnt vmcnt(8) so the next tile's DMA stays in flight
//  across the barrier (the m97/hipBLASLt lesson). 512 persistent blocks
//  (2/CU) also remove any CP dispatch-rate effect (R1 churned 16384).

typedef float fx4 __attribute__((ext_vector_type(4)));

constexpr int T = 32;
constexpr float TAU = 0.25f;
constexpr float VTH = 0.5f;
constexpr int QPR = T / 4;             // 8 fx4 per row
constexpr int BLOCK = 256;
constexpr int TILE_F4 = BLOCK * QPR;   // 2048 fx4 = 32 KB tile
constexpr int TPB = 8;                 // tiles per block (4096 tiles total)
constexpr int GRID = 512;              // 2 blocks per CU exactly

typedef const __attribute__((address_space(1))) void* gas_t;
typedef __attribute__((address_space(3))) void* las_t;

// Issue one tile's global->LDS DMA: 8 instrs/thread, 16 B/lane, lane-consecutive
// (satisfies the wave-uniform-base + lane*16 constraint; LDS mirrors global).
__device__ __forceinline__ void dma_tile(const fx4* __restrict__ g, fx4* l, int tid) {
#pragma unroll
    for (int j = 0; j < QPR; ++j) {
        __builtin_amdgcn_global_load_lds((gas_t)(g + j * BLOCK + tid),
                                         (las_t)(l + j * BLOCK + tid), 16, 0, 0);
    }
}

// Scan own row (row = tid) from linear-layout LDS, write spikes back in place.
// Per-lane rotated order (j+tid)&7 spreads the 64 lanes over all 32 banks
// (linear row-major would put every lane on the same 4-bank group).
__device__ __forceinline__ void process_tile(fx4* buf, int tid) {
    fx4 v[QPR];
#pragma unroll
    for (int j = 0; j < QPR; ++j) {
        int jj = (j + tid) & 7;
        v[jj] = buf[tid * QPR + jj];
    }
    float u = 0.0f, o = 0.0f;
#pragma unroll
    for (int j = 0; j < QPR; ++j) {
        fx4 a = v[j], r;
        u = TAU * u * (1.0f - o) + a.x; o = (u > VTH) ? 1.0f : 0.0f; r.x = o;
        u = TAU * u * (1.0f - o) + a.y; o = (u > VTH) ? 1.0f : 0.0f; r.y = o;
        u = TAU * u * (1.0f - o) + a.z; o = (u > VTH) ? 1.0f : 0.0f; r.z = o;
        u = TAU * u * (1.0f - o) + a.w; o = (u > VTH) ? 1.0f : 0.0f; r.w = o;
        v[j] = r;
    }
#pragma unroll
    for (int j = 0; j < QPR; ++j) {
        int jj = (j + tid) & 7;
        buf[tid * QPR + jj] = v[jj];
    }
}

// Fully-coalesced LDS -> global store phase (16 B/lane, lane-consecutive).
__device__ __forceinline__ void store_tile(fx4* __restrict__ g, const fx4* buf, int tid) {
#pragma unroll
    for (int j = 0; j < QPR; ++j) g[j * BLOCK + tid] = buf[j * BLOCK + tid];
}

#define SB()    __builtin_amdgcn_sched_barrier(0)
#define BARR()  __builtin_amdgcn_s_barrier()
#define WAIT_VM8()  __builtin_amdgcn_s_waitcnt(0xF78)   // vmcnt(8), ignore lgkm/exp
#define WAIT_VM0()  __builtin_amdgcn_s_waitcnt(0xF70)   // vmcnt(0), ignore lgkm/exp
#define WAIT_LGKM0() __builtin_amdgcn_s_waitcnt(0xC07F) // lgkmcnt(0), ignore vm/exp

__global__ __launch_bounds__(BLOCK, 2) void LIFSpike_kernel(
    const fx4* __restrict__ x, fx4* __restrict__ out) {
    __shared__ fx4 bufA[TILE_F4];  // 32 KB
    __shared__ fx4 bufB[TILE_F4];  // 32 KB
    const int tid = threadIdx.x;
    const int b = blockIdx.x;
    // XCD-contiguous swizzle: XCD i streams one dense 32 MiB slab.
    const int chunk = (b & 7) * (GRID / 8) + (b >> 3);
    const fx4* __restrict__ xq = x + (size_t)chunk * TPB * TILE_F4;
    fx4* __restrict__ oq = out + (size_t)chunk * TPB * TILE_F4;

    dma_tile(xq, bufA, tid);  // tile 0 -> A

#pragma unroll
    for (int i = 0; i < TPB / 2; ++i) {
        // ---- stage 1: prefetch tile 2i+1 -> B, consume A (tile 2i) ----
        dma_tile(xq + (size_t)(2 * i + 1) * TILE_F4, bufB, tid);
        SB();
        WAIT_VM8();   // tile 2i's 8 DMAs landed; 2i+1's stay in flight
        BARR();
        SB();
        process_tile(bufA, tid);
        SB();
        WAIT_LGKM0(); // own writebacks complete
        BARR();       // all threads' writebacks visible
        SB();
        store_tile(oq + (size_t)(2 * i) * TILE_F4, bufA, tid);
        SB();
        BARR();       // A reusable (everyone's store-phase reads done)
        SB();

        // ---- stage 2: prefetch tile 2i+2 -> A, consume B (tile 2i+1) ----
        if (2 * i + 2 < TPB) {
            dma_tile(xq + (size_t)(2 * i + 2) * TILE_F4, bufA, tid);
            SB();
            WAIT_VM8();
        } else {
            WAIT_VM0();
        }
        BARR();
        SB();
        process_tile(bufB, tid);
        SB();
        WAIT_LGKM0();
        BARR();
        SB();
        store_tile(oq + (size_t)(2 * i + 1) * TILE_F4, bufB, tid);
        SB();
        BARR();       // B reusable
        SB();
    }
}

extern "C" void kernel_launch(void* const* d_in, const int* in_sizes, int n_in,
                              void* d_out, int out_size, void* d_ws, size_t ws_size,
                              hipStream_t stream) {
    const fx4* x = (const fx4*)d_in[0];
    fx4* out = (fx4*)d_out;
    // 16*128*512*32 floats = 8,388,608 fx4 = 4096 tiles = 512 blocks x 8 tiles.
    LIFSpike_kernel<<<GRID, BLOCK, 0, stream>>>(x, out);
}